// Round 5
// baseline (359.038 us; speedup 1.0000x reference)
//
#include <hip/hip_runtime.h>
#include <hip/hip_cooperative_groups.h>

namespace cg = cooperative_groups;

// Averaged Hausdorff distance between two 16384x3 fp32 point sets.
// R4 (resubmitted R5 — R4 bench hit GPUAcquisitionTimeout, never ran):
//  (a) ONE fused cooperative kernel (init -> pair -> reduce -> finalize with
//      grid.sync between phases). R2/R3 both lost ~51us to 4 dispatches of
//      launch/gap overhead on ~59us of real work.
//  (b) pair phase: no LDS at all. Inner (B) points are wave-uniform -> read
//      directly from the never-written __restrict__ inputs (compiler emits
//      scalar/broadcast loads). No barrier, no LDS pipe, no lgkm stalls.
//  (c) hoist |a|^2 out of the min: min_j d^2 = |a|^2 + min_j(|b|^2 - 2 a.b);
//      seed the fma chain with |b|^2 -> 3 fma/pair + amortized min3.
// min via atomicMin on float bit patterns of clamped d^2 (>= 0).

#define NPTS   16384
#define BLK    256
#define P      8                    // outer points per thread
#define CHUNK  256                  // inner points per block
#define XBLK   (NPTS / (BLK * P))   // 8
#define SPLIT  (NPTS / CHUNK)       // 64
#define GRID   (XBLK * SPLIT * 2)   // 1024 = 4 blocks/CU -> coop-resident

__device__ __forceinline__
void phaseA(int gtid, unsigned int* rowmin, unsigned int* colmin, double* accum) {
    if (gtid < NPTS) { rowmin[gtid] = 0x7F7FFFFFu; colmin[gtid] = 0x7F7FFFFFu; }
    if (gtid == 0) *accum = 0.0;
}

__device__ __forceinline__
void phaseB(int bid, int tid, const float* __restrict__ s1, const float* __restrict__ s2,
            unsigned int* __restrict__ rowmin, unsigned int* __restrict__ colmin) {
    const int x   = bid & (XBLK - 1);
    const int y   = (bid >> 3) & (SPLIT - 1);
    const int dir = bid >> 9;
    const float* __restrict__ A = dir ? s2 : s1;
    const float* __restrict__ B = dir ? s1 : s2;
    unsigned int* __restrict__ outmin = dir ? colmin : rowmin;

    const int obase = x * (BLK * P);
    const int cbase = y * CHUNK;

    float m2x[P], m2y[P], m2z[P], sa[P], mn[P];
    #pragma unroll
    for (int p = 0; p < P; ++p) {
        int i = obase + p * BLK + tid;
        float ax = A[3 * i], ay = A[3 * i + 1], az = A[3 * i + 2];
        sa[p]  = fmaf(ax, ax, fmaf(ay, ay, az * az));   // |a|^2
        m2x[p] = -(ax + ax); m2y[p] = -(ay + ay); m2z[p] = -(az + az);
        mn[p]  = 3.402823466e+38f;
    }

    for (int j = 0; j < CHUNK; j += 8) {
        const float* bp = B + 3 * (cbase + j);   // wave-uniform address
        float bx[8], by[8], bz[8], sb[8];
        #pragma unroll
        for (int q = 0; q < 8; ++q) {
            bx[q] = bp[3 * q]; by[q] = bp[3 * q + 1]; bz[q] = bp[3 * q + 2];
            sb[q] = fmaf(bx[q], bx[q], fmaf(by[q], by[q], bz[q] * bz[q]));  // |b|^2
        }
        #pragma unroll
        for (int p = 0; p < P; ++p) {
            float t[8];
            #pragma unroll
            for (int q = 0; q < 8; ++q) {
                // |b|^2 - 2 a.b : 3 fma, seeded with sb
                t[q] = fmaf(m2x[p], bx[q],
                       fmaf(m2y[p], by[q],
                       fmaf(m2z[p], bz[q], sb[q])));
            }
            // chain maps to 4x v_min3_f32
            float u = fminf(fminf(mn[p], t[0]), t[1]);
            u = fminf(fminf(u, t[2]), t[3]);
            u = fminf(fminf(u, t[4]), t[5]);
            u = fminf(fminf(u, t[6]), t[7]);
            mn[p] = u;
        }
    }

    #pragma unroll
    for (int p = 0; p < P; ++p) {
        float d2 = fmaxf(sa[p] + mn[p], 0.0f);   // clamp keeps bit-order trick valid
        atomicMin(&outmin[obase + p * BLK + tid], __float_as_uint(d2));
    }
}

__device__ __forceinline__
void phaseC(int bid, int tid, const unsigned int* __restrict__ rowmin,
            const unsigned int* __restrict__ colmin, double* __restrict__ accum) {
    if (bid < NPTS / BLK) {           // 64 blocks cover all 16384 points
        const int i = bid * BLK + tid;
        double s = (double)sqrtf(__uint_as_float(rowmin[i]))
                 + (double)sqrtf(__uint_as_float(colmin[i]));
        for (int off = 32; off > 0; off >>= 1) s += __shfl_down(s, off);
        __shared__ double w[4];
        if ((tid & 63) == 0) w[tid >> 6] = s;
        __syncthreads();
        if (tid == 0) atomicAdd(accum, w[0] + w[1] + w[2] + w[3]);
    }
}

__global__ __launch_bounds__(BLK, 4)
void fused_kernel(const float* __restrict__ s1, const float* __restrict__ s2,
                  unsigned int* __restrict__ rowmin, unsigned int* __restrict__ colmin,
                  double* __restrict__ accum, float* __restrict__ out) {
    cg::grid_group grid = cg::this_grid();
    const int tid = threadIdx.x, bid = blockIdx.x;
    phaseA(bid * BLK + tid, rowmin, colmin, accum);
    grid.sync();
    phaseB(bid, tid, s1, s2, rowmin, colmin);
    grid.sync();
    phaseC(bid, tid, rowmin, colmin, accum);
    grid.sync();
    if (bid == 0 && tid == 0) out[0] = (float)(accum[0] / (double)NPTS);
}

// ---- fallback path (plain kernels) in case cooperative launch fails ----
__global__ __launch_bounds__(BLK)
void initk(unsigned int* rowmin, unsigned int* colmin, double* accum) {
    phaseA(blockIdx.x * BLK + threadIdx.x, rowmin, colmin, accum);
}
__global__ __launch_bounds__(BLK, 4)
void pairk(const float* __restrict__ s1, const float* __restrict__ s2,
           unsigned int* __restrict__ rowmin, unsigned int* __restrict__ colmin) {
    phaseB(blockIdx.x, threadIdx.x, s1, s2, rowmin, colmin);
}
__global__ __launch_bounds__(BLK)
void reducek(const unsigned int* __restrict__ rowmin, const unsigned int* __restrict__ colmin,
             double* __restrict__ accum) {
    phaseC(blockIdx.x, threadIdx.x, rowmin, colmin, accum);
}
__global__ void finalk(const double* __restrict__ accum, float* __restrict__ out) {
    out[0] = (float)(accum[0] / (double)NPTS);
}

extern "C" void kernel_launch(void* const* d_in, const int* in_sizes, int n_in,
                              void* d_out, int out_size, void* d_ws, size_t ws_size,
                              hipStream_t stream) {
    const float* s1 = (const float*)d_in[0];
    const float* s2 = (const float*)d_in[1];
    float* out = (float*)d_out;

    unsigned int* rowmin = (unsigned int*)d_ws;     // NPTS u32
    unsigned int* colmin = rowmin + NPTS;           // NPTS u32
    double* accum = (double*)(colmin + NPTS);       // 8B

    void* args[] = { (void*)&s1, (void*)&s2, (void*)&rowmin, (void*)&colmin,
                     (void*)&accum, (void*)&out };
    hipError_t err = hipLaunchCooperativeKernel((const void*)fused_kernel,
                                                dim3(GRID), dim3(BLK), args, 0, stream);
    if (err != hipSuccess) {
        // deterministic fallback: same phases as discrete kernels
        initk<<<NPTS / BLK, BLK, 0, stream>>>(rowmin, colmin, accum);
        pairk<<<GRID, BLK, 0, stream>>>(s1, s2, rowmin, colmin);
        reducek<<<NPTS / BLK, BLK, 0, stream>>>(rowmin, colmin, accum);
        finalk<<<1, 1, 0, stream>>>(accum, out);
    }
}

// Round 7
// 336.876 us; speedup vs baseline: 1.0658x; 1.0658x over previous
//
#include <hip/hip_runtime.h>
#include <hip/hip_cooperative_groups.h>

namespace cg = cooperative_groups;

// Averaged Hausdorff distance between two 16384x3 fp32 point sets.
// (R6 resubmitted as R7 — R6 bench hit GPUAcquisitionTimeout, never ran.)
// R5 -> R6 post-mortem: R5's no-LDS pair loop was latency-bound (real VALU
// issue ~9%): uniform global loads in the hot loop re-pay memory latency
// every 8-point batch. LDS staging pays it once per 256-pt tile.
// R6 = single cooperative dispatch (proven co-resident in R5, and total-vs-
// kernel gap is ~50us FIXED harness overhead, so fusion still right) with
// R3's proven LDS-staged loop + 3-fma form:
//   tile = float4(bx,by,bz,|b|^2);  t = fma(-2ax,bx, fma(-2ay,by, fma(-2az,bz,|b|^2)))
//   min_j d^2 = |a|^2 + min_j t   -> ~3.5 VALU ops/pair incl. min3 chain.
// min via atomicMin on float bit patterns of clamped d^2 (>= 0).

#define NPTS   16384
#define BLK    256
#define P      8                    // outer points per thread
#define CHUNK  256                  // inner points per LDS tile (== BLK)
#define XBLK   (NPTS / (BLK * P))   // 8
#define SPLIT  (NPTS / CHUNK)       // 64
#define GRID   (XBLK * SPLIT * 2)   // 1024 = 4 blocks/CU -> coop-resident

__device__ __forceinline__
void phaseA(int gtid, unsigned int* rowmin, unsigned int* colmin, double* accum) {
    if (gtid < NPTS) { rowmin[gtid] = 0x7F7FFFFFu; colmin[gtid] = 0x7F7FFFFFu; }
    if (gtid == 0) *accum = 0.0;
}

__device__ __forceinline__
void phaseB(int bid, int tid, const float* __restrict__ s1, const float* __restrict__ s2,
            unsigned int* __restrict__ rowmin, unsigned int* __restrict__ colmin) {
    __shared__ float4 tile[CHUNK];

    const int x   = bid & (XBLK - 1);
    const int y   = (bid >> 3) & (SPLIT - 1);
    const int dir = bid >> 9;
    const float* __restrict__ A = dir ? s2 : s1;
    const float* __restrict__ B = dir ? s1 : s2;
    unsigned int* __restrict__ outmin = dir ? colmin : rowmin;

    const int obase = x * (BLK * P);
    const int cbase = y * CHUNK;

    // Stage inner tile: float4(bx,by,bz,|b|^2). Latency paid ONCE per tile.
    {
        int g = cbase + tid;
        float bx = B[3 * g], by = B[3 * g + 1], bz = B[3 * g + 2];
        tile[tid] = make_float4(bx, by, bz, fmaf(bx, bx, fmaf(by, by, bz * bz)));
    }
    __syncthreads();

    float m2x[P], m2y[P], m2z[P], sa[P], mn[P];
    #pragma unroll
    for (int p = 0; p < P; ++p) {
        int i = obase + p * BLK + tid;
        float ax = A[3 * i], ay = A[3 * i + 1], az = A[3 * i + 2];
        sa[p]  = fmaf(ax, ax, fmaf(ay, ay, az * az));   // |a|^2
        m2x[p] = -(ax + ax); m2y[p] = -(ay + ay); m2z[p] = -(az + az);
        mn[p]  = 3.402823466e+38f;
    }

    // One broadcast ds_read_b128 serves P*64 = 512 pairs; 3 fma/pair + min3.
    for (int j = 0; j < CHUNK; j += 4) {
        float4 b0 = tile[j], b1 = tile[j + 1], b2 = tile[j + 2], b3 = tile[j + 3];
        #pragma unroll
        for (int p = 0; p < P; ++p) {
            float t0 = fmaf(m2x[p], b0.x, fmaf(m2y[p], b0.y, fmaf(m2z[p], b0.z, b0.w)));
            float t1 = fmaf(m2x[p], b1.x, fmaf(m2y[p], b1.y, fmaf(m2z[p], b1.z, b1.w)));
            float t2 = fmaf(m2x[p], b2.x, fmaf(m2y[p], b2.y, fmaf(m2z[p], b2.z, b2.w)));
            float t3 = fmaf(m2x[p], b3.x, fmaf(m2y[p], b3.y, fmaf(m2z[p], b3.z, b3.w)));
            // 2x v_min3_f32
            float u = fminf(fminf(mn[p], t0), t1);
            mn[p] = fminf(fminf(u, t2), t3);
        }
    }

    #pragma unroll
    for (int p = 0; p < P; ++p) {
        float d2 = fmaxf(sa[p] + mn[p], 0.0f);   // clamp keeps bit-order trick valid
        atomicMin(&outmin[obase + p * BLK + tid], __float_as_uint(d2));
    }
}

__device__ __forceinline__
void phaseC(int bid, int tid, const unsigned int* __restrict__ rowmin,
            const unsigned int* __restrict__ colmin, double* __restrict__ accum) {
    if (bid < NPTS / BLK) {           // 64 blocks cover all 16384 points
        const int i = bid * BLK + tid;
        double s = (double)sqrtf(__uint_as_float(rowmin[i]))
                 + (double)sqrtf(__uint_as_float(colmin[i]));
        for (int off = 32; off > 0; off >>= 1) s += __shfl_down(s, off);
        __shared__ double w[4];
        if ((tid & 63) == 0) w[tid >> 6] = s;
        __syncthreads();
        if (tid == 0) atomicAdd(accum, w[0] + w[1] + w[2] + w[3]);
    }
}

__global__ __launch_bounds__(BLK, 4)
void fused_kernel(const float* __restrict__ s1, const float* __restrict__ s2,
                  unsigned int* __restrict__ rowmin, unsigned int* __restrict__ colmin,
                  double* __restrict__ accum, float* __restrict__ out) {
    cg::grid_group grid = cg::this_grid();
    const int tid = threadIdx.x, bid = blockIdx.x;
    phaseA(bid * BLK + tid, rowmin, colmin, accum);
    grid.sync();
    phaseB(bid, tid, s1, s2, rowmin, colmin);
    grid.sync();
    phaseC(bid, tid, rowmin, colmin, accum);
    grid.sync();
    if (bid == 0 && tid == 0) out[0] = (float)(accum[0] / (double)NPTS);
}

// ---- fallback path (plain kernels) in case cooperative launch fails ----
__global__ __launch_bounds__(BLK)
void initk(unsigned int* rowmin, unsigned int* colmin, double* accum) {
    phaseA(blockIdx.x * BLK + threadIdx.x, rowmin, colmin, accum);
}
__global__ __launch_bounds__(BLK, 4)
void pairk(const float* __restrict__ s1, const float* __restrict__ s2,
           unsigned int* __restrict__ rowmin, unsigned int* __restrict__ colmin) {
    phaseB(blockIdx.x, threadIdx.x, s1, s2, rowmin, colmin);
}
__global__ __launch_bounds__(BLK)
void reducek(const unsigned int* __restrict__ rowmin, const unsigned int* __restrict__ colmin,
             double* __restrict__ accum) {
    phaseC(blockIdx.x, threadIdx.x, rowmin, colmin, accum);
}
__global__ void finalk(const double* __restrict__ accum, float* __restrict__ out) {
    out[0] = (float)(accum[0] / (double)NPTS);
}

extern "C" void kernel_launch(void* const* d_in, const int* in_sizes, int n_in,
                              void* d_out, int out_size, void* d_ws, size_t ws_size,
                              hipStream_t stream) {
    const float* s1 = (const float*)d_in[0];
    const float* s2 = (const float*)d_in[1];
    float* out = (float*)d_out;

    unsigned int* rowmin = (unsigned int*)d_ws;     // NPTS u32
    unsigned int* colmin = rowmin + NPTS;           // NPTS u32
    double* accum = (double*)(colmin + NPTS);       // 8B

    void* args[] = { (void*)&s1, (void*)&s2, (void*)&rowmin, (void*)&colmin,
                     (void*)&accum, (void*)&out };
    hipError_t err = hipLaunchCooperativeKernel((const void*)fused_kernel,
                                                dim3(GRID), dim3(BLK), args, 0, stream);
    if (err != hipSuccess) {
        // deterministic fallback: same phases as discrete kernels
        initk<<<NPTS / BLK, BLK, 0, stream>>>(rowmin, colmin, accum);
        pairk<<<GRID, BLK, 0, stream>>>(s1, s2, rowmin, colmin);
        reducek<<<NPTS / BLK, BLK, 0, stream>>>(rowmin, colmin, accum);
        finalk<<<1, 1, 0, stream>>>(accum, out);
    }
}

// Round 9
// 138.377 us; speedup vs baseline: 2.5946x; 2.4345x over previous
//
#include <hip/hip_runtime.h>
#include <hip/hip_bf16.h>
#include <math.h>

// Averaged Hausdorff distance between two 16384x3 fp32 point sets.
// (R8 resubmitted as R9 — R8 bench hit GPUAcquisitionTimeout, never ran.)
// R7 post-mortem: fused cooperative kernel was dominated by grid.sync()
// (~70us each x3 on 1024 blocks across 8 non-coherent XCD L2s): R5 (slow
// loop) 306us ~= R7 (fast loop) 280us. Meanwhile total-kernel gap is ~50us
// FIXED regardless of dispatch count -> discrete kernels are fine.
// R8 = discrete 3-kernel pipeline, no atomics, no init:
//   1) pair_part: LDS-tiled 3-fma inner loop (t = fma(-2a, b, |b|^2) chain),
//      P=16 outer pts/thread (halves LDS-read cost/pair vs P=8, which was
//      ~86% of VALU cost and capped R3 at ~55% issue). Writes partial min
//      d^2 per (dir, chunk, point) with plain coalesced stores.
//   2) reduce_part: min over chunks, sqrt, block partial sums (double).
//   3) final: sum 64 block sums, divide, store.
// Fallback (ws too small): R3-style atomicMin path.

#define NPTS   16384
#define BLK    256
#define P      16                   // outer points per thread
#define CHUNK  128                  // inner points per LDS tile
#define XBLK   (NPTS / (BLK * P))   // 4
#define SPLIT  (NPTS / CHUNK)       // 128
#define RBLK   (NPTS / BLK)         // 64 reduce blocks
#define FLTMAX 3.402823466e+38f

// ---------------- main path (no atomics) ----------------

__global__ __launch_bounds__(BLK, 4)
void pair_part_kernel(const float* __restrict__ s1, const float* __restrict__ s2,
                      float* __restrict__ part /* [2][SPLIT][NPTS] */) {
    __shared__ float4 tile[CHUNK];

    const int tid = threadIdx.x;
    const int x   = blockIdx.x;
    const int y   = blockIdx.y;
    const int dir = blockIdx.z;
    const float* __restrict__ A = dir ? s2 : s1;
    const float* __restrict__ B = dir ? s1 : s2;

    const int obase = x * (BLK * P);
    const int cbase = y * CHUNK;

    // Stage inner tile once: float4(bx,by,bz,|b|^2).
    if (tid < CHUNK) {
        int g = cbase + tid;
        float bx = B[3 * g], by = B[3 * g + 1], bz = B[3 * g + 2];
        tile[tid] = make_float4(bx, by, bz, fmaf(bx, bx, fmaf(by, by, bz * bz)));
    }
    __syncthreads();

    float m2x[P], m2y[P], m2z[P], sa[P], mn[P];
    #pragma unroll
    for (int p = 0; p < P; ++p) {
        int i = obase + p * BLK + tid;
        float ax = A[3 * i], ay = A[3 * i + 1], az = A[3 * i + 2];
        sa[p]  = fmaf(ax, ax, fmaf(ay, ay, az * az));   // |a|^2
        m2x[p] = -(ax + ax); m2y[p] = -(ay + ay); m2z[p] = -(az + az);
        mn[p]  = FLTMAX;
    }

    // One broadcast ds_read_b128 serves P*64 = 1024 pairs.
    // 3 fma/pair + 0.5 min3/pair: ~3.5 VALU ops/pair.
    for (int j = 0; j < CHUNK; j += 4) {
        float4 b0 = tile[j], b1 = tile[j + 1], b2 = tile[j + 2], b3 = tile[j + 3];
        #pragma unroll
        for (int p = 0; p < P; ++p) {
            float t0 = fmaf(m2x[p], b0.x, fmaf(m2y[p], b0.y, fmaf(m2z[p], b0.z, b0.w)));
            float t1 = fmaf(m2x[p], b1.x, fmaf(m2y[p], b1.y, fmaf(m2z[p], b1.z, b1.w)));
            float t2 = fmaf(m2x[p], b2.x, fmaf(m2y[p], b2.y, fmaf(m2z[p], b2.z, b2.w)));
            float t3 = fmaf(m2x[p], b3.x, fmaf(m2y[p], b3.y, fmaf(m2z[p], b3.z, b3.w)));
            float u = fminf(fminf(mn[p], t0), t1);   // 2x v_min3_f32
            mn[p] = fminf(fminf(u, t2), t3);
        }
    }

    // Plain coalesced stores of partial min d^2 (clamped >= 0).
    float* dst = part + ((size_t)dir * SPLIT + y) * NPTS + obase;
    #pragma unroll
    for (int p = 0; p < P; ++p) {
        dst[p * BLK + tid] = fmaxf(sa[p] + mn[p], 0.0f);
    }
}

__global__ __launch_bounds__(BLK)
void reduce_part_kernel(const float* __restrict__ part, double* __restrict__ blocksum) {
    const int tid = threadIdx.x;
    const int i = blockIdx.x * BLK + tid;

    float r = FLTMAX, c = FLTMAX;
    const float* rp = part + i;                       // dir 0
    const float* cp = part + (size_t)SPLIT * NPTS + i; // dir 1
    for (int y = 0; y < SPLIT; ++y) r = fminf(r, rp[(size_t)y * NPTS]);
    for (int y = 0; y < SPLIT; ++y) c = fminf(c, cp[(size_t)y * NPTS]);

    double s = (double)sqrtf(r) + (double)sqrtf(c);
    for (int off = 32; off > 0; off >>= 1) s += __shfl_down(s, off);
    __shared__ double w[4];
    if ((tid & 63) == 0) w[tid >> 6] = s;
    __syncthreads();
    if (tid == 0) blocksum[blockIdx.x] = w[0] + w[1] + w[2] + w[3];
}

__global__ void final_kernel(const double* __restrict__ blocksum, float* __restrict__ out) {
    const int lane = threadIdx.x;     // 64 threads
    double s = blocksum[lane];
    for (int off = 32; off > 0; off >>= 1) s += __shfl_down(s, off);
    if (lane == 0) out[0] = (float)(s / (double)NPTS);
}

// ---------------- fallback path (atomicMin, small ws) ----------------

__global__ __launch_bounds__(BLK)
void fb_init(unsigned int* rowmin, unsigned int* colmin) {
    int i = blockIdx.x * BLK + threadIdx.x;
    if (i < NPTS) { rowmin[i] = 0x7F7FFFFFu; colmin[i] = 0x7F7FFFFFu; }
}

__global__ __launch_bounds__(BLK, 4)
void fb_pair(const float* __restrict__ s1, const float* __restrict__ s2,
             unsigned int* __restrict__ rowmin, unsigned int* __restrict__ colmin) {
    __shared__ float4 tile[CHUNK];
    const int tid = threadIdx.x;
    const int dir = blockIdx.z;
    const float* __restrict__ A = dir ? s2 : s1;
    const float* __restrict__ B = dir ? s1 : s2;
    unsigned int* __restrict__ outmin = dir ? colmin : rowmin;
    const int obase = blockIdx.x * (BLK * P);
    const int cbase = blockIdx.y * CHUNK;

    if (tid < CHUNK) {
        int g = cbase + tid;
        float bx = B[3 * g], by = B[3 * g + 1], bz = B[3 * g + 2];
        tile[tid] = make_float4(bx, by, bz, fmaf(bx, bx, fmaf(by, by, bz * bz)));
    }
    __syncthreads();

    float m2x[P], m2y[P], m2z[P], sa[P], mn[P];
    #pragma unroll
    for (int p = 0; p < P; ++p) {
        int i = obase + p * BLK + tid;
        float ax = A[3 * i], ay = A[3 * i + 1], az = A[3 * i + 2];
        sa[p]  = fmaf(ax, ax, fmaf(ay, ay, az * az));
        m2x[p] = -(ax + ax); m2y[p] = -(ay + ay); m2z[p] = -(az + az);
        mn[p]  = FLTMAX;
    }
    for (int j = 0; j < CHUNK; j += 4) {
        float4 b0 = tile[j], b1 = tile[j + 1], b2 = tile[j + 2], b3 = tile[j + 3];
        #pragma unroll
        for (int p = 0; p < P; ++p) {
            float t0 = fmaf(m2x[p], b0.x, fmaf(m2y[p], b0.y, fmaf(m2z[p], b0.z, b0.w)));
            float t1 = fmaf(m2x[p], b1.x, fmaf(m2y[p], b1.y, fmaf(m2z[p], b1.z, b1.w)));
            float t2 = fmaf(m2x[p], b2.x, fmaf(m2y[p], b2.y, fmaf(m2z[p], b2.z, b2.w)));
            float t3 = fmaf(m2x[p], b3.x, fmaf(m2y[p], b3.y, fmaf(m2z[p], b3.z, b3.w)));
            float u = fminf(fminf(mn[p], t0), t1);
            mn[p] = fminf(fminf(u, t2), t3);
        }
    }
    #pragma unroll
    for (int p = 0; p < P; ++p) {
        float d2 = fmaxf(sa[p] + mn[p], 0.0f);
        atomicMin(&outmin[obase + p * BLK + tid], __float_as_uint(d2));
    }
}

__global__ __launch_bounds__(BLK)
void fb_reduce(const unsigned int* __restrict__ rowmin, const unsigned int* __restrict__ colmin,
               double* __restrict__ blocksum) {
    const int tid = threadIdx.x;
    const int i = blockIdx.x * BLK + tid;
    double s = (double)sqrtf(__uint_as_float(rowmin[i]))
             + (double)sqrtf(__uint_as_float(colmin[i]));
    for (int off = 32; off > 0; off >>= 1) s += __shfl_down(s, off);
    __shared__ double w[4];
    if ((tid & 63) == 0) w[tid >> 6] = s;
    __syncthreads();
    if (tid == 0) blocksum[blockIdx.x] = w[0] + w[1] + w[2] + w[3];
}

// ---------------- launch ----------------

extern "C" void kernel_launch(void* const* d_in, const int* in_sizes, int n_in,
                              void* d_out, int out_size, void* d_ws, size_t ws_size,
                              hipStream_t stream) {
    const float* s1 = (const float*)d_in[0];
    const float* s2 = (const float*)d_in[1];
    float* out = (float*)d_out;

    const size_t part_elems = (size_t)2 * SPLIT * NPTS;          // 4M floats = 16 MB
    const size_t need = part_elems * sizeof(float) + RBLK * sizeof(double);

    if (ws_size >= need) {
        float* part = (float*)d_ws;
        double* blocksum = (double*)(part + part_elems);         // 16MB offset, 8B-aligned

        dim3 grid(XBLK, SPLIT, 2);                               // 4 x 128 x 2 = 1024
        pair_part_kernel<<<grid, BLK, 0, stream>>>(s1, s2, part);
        reduce_part_kernel<<<RBLK, BLK, 0, stream>>>(part, blocksum);
        final_kernel<<<1, 64, 0, stream>>>(blocksum, out);
    } else {
        unsigned int* rowmin = (unsigned int*)d_ws;
        unsigned int* colmin = rowmin + NPTS;
        double* blocksum = (double*)(colmin + NPTS);

        fb_init<<<NPTS / BLK, BLK, 0, stream>>>(rowmin, colmin);
        dim3 grid(XBLK, SPLIT, 2);
        fb_pair<<<grid, BLK, 0, stream>>>(s1, s2, rowmin, colmin);
        fb_reduce<<<RBLK, BLK, 0, stream>>>(rowmin, colmin, blocksum);
        final_kernel<<<1, 64, 0, stream>>>(blocksum, out);
    }
}

// Round 12
// 106.862 us; speedup vs baseline: 3.3598x; 1.2949x over previous
//
#include <hip/hip_runtime.h>
#include <hip/hip_bf16.h>
#include <math.h>

// Averaged Hausdorff distance between two 16384x3 fp32 point sets.
// (R10 resubmitted as R12 — R10 and R11 benches both hit GPUAcquisitionTimeout,
// kernel has never run.)
// R9 post-mortem: (1) VGPR_Count=64 with P=16 (needs ~110) => compiler
// restructured/spilled under launch_bounds(256,4)'s 128-VGPR cap (WRITE_SIZE
// had ~5.7MB of scratch stores). (2) total-kernel gap grew 50->87us: the
// 64-block strided reduce over a 16.8MB part array + its poison cost.
// R10: (a) launch_bounds(256,2) -> 256-VGPR cap, P=16 lives in registers;
//      (b) CHUNK=256 -> part array halves to 8MB, grid (4,64,2)=512;
//      (c) reduce parallelized: 128 blocks (dir in grid.y), 64 unrolled
//          independent loads/thread.
// Inner loop unchanged: t = fma(-2a,b,|b|^2) chain, min3; d^2 clamped >= 0.

#define NPTS   16384
#define BLK    256
#define P      16                   // outer points per thread
#define CHUNK  256                  // inner points per LDS tile
#define XBLK   (NPTS / (BLK * P))   // 4
#define SPLIT  (NPTS / CHUNK)       // 64
#define RBLK   (NPTS / BLK)         // 64 reduce blocks per dir
#define FLTMAX 3.402823466e+38f

// ---------------- main path (no atomics) ----------------

__global__ __launch_bounds__(BLK, 2)
void pair_part_kernel(const float* __restrict__ s1, const float* __restrict__ s2,
                      float* __restrict__ part /* [2][SPLIT][NPTS] */) {
    __shared__ float4 tile[CHUNK];

    const int tid = threadIdx.x;
    const int x   = blockIdx.x;
    const int y   = blockIdx.y;
    const int dir = blockIdx.z;
    const float* __restrict__ A = dir ? s2 : s1;
    const float* __restrict__ B = dir ? s1 : s2;

    const int obase = x * (BLK * P);
    const int cbase = y * CHUNK;

    // Stage inner tile once: float4(bx,by,bz,|b|^2). CHUNK == BLK.
    {
        int g = cbase + tid;
        float bx = B[3 * g], by = B[3 * g + 1], bz = B[3 * g + 2];
        tile[tid] = make_float4(bx, by, bz, fmaf(bx, bx, fmaf(by, by, bz * bz)));
    }
    __syncthreads();

    float m2x[P], m2y[P], m2z[P], sa[P], mn[P];
    #pragma unroll
    for (int p = 0; p < P; ++p) {
        int i = obase + p * BLK + tid;
        float ax = A[3 * i], ay = A[3 * i + 1], az = A[3 * i + 2];
        sa[p]  = fmaf(ax, ax, fmaf(ay, ay, az * az));   // |a|^2
        m2x[p] = -(ax + ax); m2y[p] = -(ay + ay); m2z[p] = -(az + az);
        mn[p]  = FLTMAX;
    }

    // One broadcast ds_read_b128 serves P*64 = 1024 pairs.
    // Per j-iter: 4 ds_read (~48 cyc) vs 224 VALU (~448 cyc) -> VALU-bound.
    for (int j = 0; j < CHUNK; j += 4) {
        float4 b0 = tile[j], b1 = tile[j + 1], b2 = tile[j + 2], b3 = tile[j + 3];
        #pragma unroll
        for (int p = 0; p < P; ++p) {
            float t0 = fmaf(m2x[p], b0.x, fmaf(m2y[p], b0.y, fmaf(m2z[p], b0.z, b0.w)));
            float t1 = fmaf(m2x[p], b1.x, fmaf(m2y[p], b1.y, fmaf(m2z[p], b1.z, b1.w)));
            float t2 = fmaf(m2x[p], b2.x, fmaf(m2y[p], b2.y, fmaf(m2z[p], b2.z, b2.w)));
            float t3 = fmaf(m2x[p], b3.x, fmaf(m2y[p], b3.y, fmaf(m2z[p], b3.z, b3.w)));
            float u = fminf(fminf(mn[p], t0), t1);   // 2x v_min3_f32
            mn[p] = fminf(fminf(u, t2), t3);
        }
    }

    // Plain coalesced stores of partial min d^2 (clamped >= 0).
    float* dst = part + ((size_t)dir * SPLIT + y) * NPTS + obase;
    #pragma unroll
    for (int p = 0; p < P; ++p) {
        dst[p * BLK + tid] = fmaxf(sa[p] + mn[p], 0.0f);
    }
}

__global__ __launch_bounds__(BLK)
void reduce_part_kernel(const float* __restrict__ part, double* __restrict__ blocksum) {
    const int tid = threadIdx.x;
    const int dir = blockIdx.y;                       // 0 or 1
    const int i = blockIdx.x * BLK + tid;

    const float* rp = part + (size_t)dir * SPLIT * NPTS + i;
    float m = FLTMAX;
    #pragma unroll 8
    for (int y = 0; y < SPLIT; ++y) m = fminf(m, rp[(size_t)y * NPTS]);

    double s = (double)sqrtf(m);
    for (int off = 32; off > 0; off >>= 1) s += __shfl_down(s, off);
    __shared__ double w[4];
    if ((tid & 63) == 0) w[tid >> 6] = s;
    __syncthreads();
    if (tid == 0) blocksum[dir * RBLK + blockIdx.x] = w[0] + w[1] + w[2] + w[3];
}

__global__ void final_kernel(const double* __restrict__ blocksum, float* __restrict__ out) {
    const int tid = threadIdx.x;      // 128 threads (2 waves)
    double s = blocksum[tid];
    for (int off = 32; off > 0; off >>= 1) s += __shfl_down(s, off);
    __shared__ double w[2];
    if ((tid & 63) == 0) w[tid >> 6] = s;
    __syncthreads();
    if (tid == 0) out[0] = (float)((w[0] + w[1]) / (double)NPTS);
}

// ---------------- fallback path (atomicMin, small ws) ----------------

__global__ __launch_bounds__(BLK)
void fb_init(unsigned int* rowmin, unsigned int* colmin) {
    int i = blockIdx.x * BLK + threadIdx.x;
    if (i < NPTS) { rowmin[i] = 0x7F7FFFFFu; colmin[i] = 0x7F7FFFFFu; }
}

__global__ __launch_bounds__(BLK, 2)
void fb_pair(const float* __restrict__ s1, const float* __restrict__ s2,
             unsigned int* __restrict__ rowmin, unsigned int* __restrict__ colmin) {
    __shared__ float4 tile[CHUNK];
    const int tid = threadIdx.x;
    const int dir = blockIdx.z;
    const float* __restrict__ A = dir ? s2 : s1;
    const float* __restrict__ B = dir ? s1 : s2;
    unsigned int* __restrict__ outmin = dir ? colmin : rowmin;
    const int obase = blockIdx.x * (BLK * P);
    const int cbase = blockIdx.y * CHUNK;

    {
        int g = cbase + tid;
        float bx = B[3 * g], by = B[3 * g + 1], bz = B[3 * g + 2];
        tile[tid] = make_float4(bx, by, bz, fmaf(bx, bx, fmaf(by, by, bz * bz)));
    }
    __syncthreads();

    float m2x[P], m2y[P], m2z[P], sa[P], mn[P];
    #pragma unroll
    for (int p = 0; p < P; ++p) {
        int i = obase + p * BLK + tid;
        float ax = A[3 * i], ay = A[3 * i + 1], az = A[3 * i + 2];
        sa[p]  = fmaf(ax, ax, fmaf(ay, ay, az * az));
        m2x[p] = -(ax + ax); m2y[p] = -(ay + ay); m2z[p] = -(az + az);
        mn[p]  = FLTMAX;
    }
    for (int j = 0; j < CHUNK; j += 4) {
        float4 b0 = tile[j], b1 = tile[j + 1], b2 = tile[j + 2], b3 = tile[j + 3];
        #pragma unroll
        for (int p = 0; p < P; ++p) {
            float t0 = fmaf(m2x[p], b0.x, fmaf(m2y[p], b0.y, fmaf(m2z[p], b0.z, b0.w)));
            float t1 = fmaf(m2x[p], b1.x, fmaf(m2y[p], b1.y, fmaf(m2z[p], b1.z, b1.w)));
            float t2 = fmaf(m2x[p], b2.x, fmaf(m2y[p], b2.y, fmaf(m2z[p], b2.z, b2.w)));
            float t3 = fmaf(m2x[p], b3.x, fmaf(m2y[p], b3.y, fmaf(m2z[p], b3.z, b3.w)));
            float u = fminf(fminf(mn[p], t0), t1);
            mn[p] = fminf(fminf(u, t2), t3);
        }
    }
    #pragma unroll
    for (int p = 0; p < P; ++p) {
        float d2 = fmaxf(sa[p] + mn[p], 0.0f);
        atomicMin(&outmin[obase + p * BLK + tid], __float_as_uint(d2));
    }
}

__global__ __launch_bounds__(BLK)
void fb_reduce(const unsigned int* __restrict__ rowmin, const unsigned int* __restrict__ colmin,
               double* __restrict__ blocksum) {
    const int tid = threadIdx.x;
    const int i = blockIdx.x * BLK + tid;
    double s = (double)sqrtf(__uint_as_float(rowmin[i]))
             + (double)sqrtf(__uint_as_float(colmin[i]));
    for (int off = 32; off > 0; off >>= 1) s += __shfl_down(s, off);
    __shared__ double w[4];
    if ((tid & 63) == 0) w[tid >> 6] = s;
    __syncthreads();
    if (tid == 0) {
        blocksum[blockIdx.x] = w[0] + w[1] + w[2] + w[3];
        blocksum[RBLK + blockIdx.x] = 0.0;   // keep final_kernel's 128-wide sum valid
    }
}

// ---------------- launch ----------------

extern "C" void kernel_launch(void* const* d_in, const int* in_sizes, int n_in,
                              void* d_out, int out_size, void* d_ws, size_t ws_size,
                              hipStream_t stream) {
    const float* s1 = (const float*)d_in[0];
    const float* s2 = (const float*)d_in[1];
    float* out = (float*)d_out;

    const size_t part_elems = (size_t)2 * SPLIT * NPTS;          // 2M floats = 8 MB
    const size_t need = part_elems * sizeof(float) + 2 * RBLK * sizeof(double);

    if (ws_size >= need) {
        float* part = (float*)d_ws;
        double* blocksum = (double*)(part + part_elems);         // 8MB offset, 8B-aligned

        dim3 grid(XBLK, SPLIT, 2);                               // 4 x 64 x 2 = 512
        pair_part_kernel<<<grid, BLK, 0, stream>>>(s1, s2, part);
        reduce_part_kernel<<<dim3(RBLK, 2), BLK, 0, stream>>>(part, blocksum);
        final_kernel<<<1, 128, 0, stream>>>(blocksum, out);
    } else {
        unsigned int* rowmin = (unsigned int*)d_ws;
        unsigned int* colmin = rowmin + NPTS;
        double* blocksum = (double*)(colmin + NPTS);

        fb_init<<<NPTS / BLK, BLK, 0, stream>>>(rowmin, colmin);
        dim3 grid(XBLK, SPLIT, 2);
        fb_pair<<<grid, BLK, 0, stream>>>(s1, s2, rowmin, colmin);
        fb_reduce<<<RBLK, BLK, 0, stream>>>(rowmin, colmin, blocksum);
        final_kernel<<<1, 128, 0, stream>>>(blocksum, out);
    }
}